// Round 1
// baseline (1218.521 us; speedup 1.0000x reference)
//
#include <hip/hip_runtime.h>
#include <cstdint>
#include <math.h>

// Problem constants
#define D_MODEL 1024
#define NHEADS  16
#define DK      64
#define BATCH   2
#define SEQ     2048
#define M_TOTAL (BATCH*SEQ)   // 4096 rows

// ---------------------------------------------------------------------------
// Generic fp32 GEMM: C[M_TOTAL][1024] = A[M_TOTAL][1024] @ B[1024][1024] + bias
// Tile: BM=128, BN=64, BK=16. 256 threads, 8x4 micro-kernel.
// LDS bank analysis: As reads are 16-lane broadcasts (free); Bs reads 2-way
// (free per m136); As transposed writes 2-way; pads keep 16B alignment.
// ---------------------------------------------------------------------------
__device__ __forceinline__ void gemm_body(const float* __restrict__ A,
                                          const float* __restrict__ B,
                                          const float* __restrict__ bias,
                                          float* __restrict__ C)
{
    __shared__ float As[16][132];   // [k][m], 132 = 128 + 4 pad (16B-aligned rows)
    __shared__ float Bs[16][68];    // [k][n], 68  = 64 + 4 pad

    const int t  = threadIdx.x;
    const int tx = t & 15;          // 16 col groups of 4
    const int ty = t >> 4;          // 16 row groups of 8
    const int m0 = blockIdx.y * 128;
    const int n0 = blockIdx.x * 64;

    float acc[8][4];
#pragma unroll
    for (int i = 0; i < 8; ++i)
#pragma unroll
        for (int j = 0; j < 4; ++j) acc[i][j] = 0.f;

    // A-tile loader mapping: 128 rows x 16 k; thread loads 2 float4 (rows r, r+64)
    const int arow = t >> 2;            // 0..63
    const int ac4  = (t & 3) * 4;       // k-offset within tile: 0,4,8,12
    // B-tile loader mapping: 16 k x 64 n; thread loads 1 float4
    const int br   = t >> 4;            // 0..15
    const int bc4  = (t & 15) * 4;      // 0..60

    for (int k0 = 0; k0 < 1024; k0 += 16) {
        // issue global loads early (overlap with previous tile's tail)
        const float4 av0 = *(const float4*)(A + (size_t)(m0 + arow     ) * 1024 + k0 + ac4);
        const float4 av1 = *(const float4*)(A + (size_t)(m0 + arow + 64) * 1024 + k0 + ac4);
        const float4 bv  = *(const float4*)(B + (size_t)(k0 + br) * 1024 + n0 + bc4);

        __syncthreads();   // previous tile fully consumed
        As[ac4 + 0][arow]      = av0.x;
        As[ac4 + 1][arow]      = av0.y;
        As[ac4 + 2][arow]      = av0.z;
        As[ac4 + 3][arow]      = av0.w;
        As[ac4 + 0][arow + 64] = av1.x;
        As[ac4 + 1][arow + 64] = av1.y;
        As[ac4 + 2][arow + 64] = av1.z;
        As[ac4 + 3][arow + 64] = av1.w;
        *(float4*)&Bs[br][bc4] = bv;
        __syncthreads();   // tiles ready

#pragma unroll
        for (int kk = 0; kk < 16; ++kk) {
            const float4 a0 = *(const float4*)&As[kk][8 * ty];
            const float4 a1 = *(const float4*)&As[kk][8 * ty + 4];
            const float4 b4 = *(const float4*)&Bs[kk][4 * tx];
            const float a[8] = {a0.x, a0.y, a0.z, a0.w, a1.x, a1.y, a1.z, a1.w};
            const float bb[4] = {b4.x, b4.y, b4.z, b4.w};
#pragma unroll
            for (int i = 0; i < 8; ++i)
#pragma unroll
                for (int j = 0; j < 4; ++j)
                    acc[i][j] = fmaf(a[i], bb[j], acc[i][j]);
        }
    }

    const float4 bb4 = *(const float4*)(bias + n0 + tx * 4);
#pragma unroll
    for (int i = 0; i < 8; ++i) {
        float4 c;
        c.x = acc[i][0] + bb4.x;
        c.y = acc[i][1] + bb4.y;
        c.z = acc[i][2] + bb4.z;
        c.w = acc[i][3] + bb4.w;
        *(float4*)(C + (size_t)(m0 + ty * 8 + i) * 1024 + n0 + tx * 4) = c;
    }
}

__global__ __launch_bounds__(256) void qkv_gemm(const float* __restrict__ x,
                                                const float* __restrict__ Wq, const float* __restrict__ bq,
                                                const float* __restrict__ Wk, const float* __restrict__ bk,
                                                const float* __restrict__ Wv, const float* __restrict__ bv,
                                                float* __restrict__ Q, float* __restrict__ K, float* __restrict__ V)
{
    const float* B; const float* bias; float* C;
    if (blockIdx.z == 0)      { B = Wq; bias = bq; C = Q; }
    else if (blockIdx.z == 1) { B = Wk; bias = bk; C = K; }
    else                      { B = Wv; bias = bv; C = V; }
    gemm_body(x, B, bias, C);
}

__global__ __launch_bounds__(256) void oproj_gemm(const float* __restrict__ A,
                                                  const float* __restrict__ Wo,
                                                  const float* __restrict__ bo,
                                                  float* __restrict__ C)
{
    gemm_body(A, Wo, bo, C);
}

// ---------------------------------------------------------------------------
// Flash attention, fp32, no masking.
// Grid: (SEQ/64 q-blocks, B*H). Block: 256 threads = 64 q-rows x 4 dim-groups.
// Each thread owns q[16], o[16] for one (row, 16-dim slice). Scores via 4-lane
// shfl_xor butterfly. K/V tiles (32 x 64) staged in LDS; all compute-phase LDS
// reads are wave-uniform per dim-group (broadcast -> conflict-free).
// Softmax in exp2 domain: scale = (1/8) * log2(e) folded into q.
// ---------------------------------------------------------------------------
__global__ __launch_bounds__(256) void attn_kernel(const float* __restrict__ Q,
                                                   const float* __restrict__ K,
                                                   const float* __restrict__ V,
                                                   float* __restrict__ O)
{
    __shared__ float Kt[32][64];
    __shared__ float Vt[32][64];

    const int t    = threadIdx.x;
    const int bh   = blockIdx.y;
    const int b    = bh >> 4;
    const int h    = bh & 15;
    const int lrow = t >> 2;     // 0..63
    const int dg   = t & 3;      // dim group: covers d = dg*16 .. dg*16+15
    const size_t mrow = (size_t)(b * SEQ + blockIdx.x * 64 + lrow);

    const float scale = 0.125f * 1.44269504088896f;  // (1/sqrt(64)) * log2(e)

    float q[16], o[16];
    {
        const float* qp = Q + mrow * D_MODEL + h * DK + dg * 16;
#pragma unroll
        for (int j4 = 0; j4 < 4; ++j4) {
            const float4 v4 = *(const float4*)(qp + 4 * j4);
            q[4 * j4 + 0] = v4.x * scale;
            q[4 * j4 + 1] = v4.y * scale;
            q[4 * j4 + 2] = v4.z * scale;
            q[4 * j4 + 3] = v4.w * scale;
        }
    }
#pragma unroll
    for (int j = 0; j < 16; ++j) o[j] = 0.f;

    float mrun = -INFINITY;
    float lsum = 0.f;

    const size_t kvbase = (size_t)(b * SEQ) * D_MODEL + h * DK;

    for (int kt = 0; kt < SEQ / 32; ++kt) {
        __syncthreads();   // previous tile fully consumed
#pragma unroll
        for (int i = 0; i < 2; ++i) {
            const int idx = t + 256 * i;          // 0..511 float4 slots
            const int r   = idx >> 4;             // 0..31 key row
            const int c4  = (idx & 15) * 4;       // 0..60
            const size_t g = kvbase + (size_t)(kt * 32 + r) * D_MODEL + c4;
            *(float4*)&Kt[r][c4] = *(const float4*)(K + g);
            *(float4*)&Vt[r][c4] = *(const float4*)(V + g);
        }
        __syncthreads();   // tile ready

        float s[32];
#pragma unroll
        for (int kk = 0; kk < 32; ++kk) {
            float acc = 0.f;
#pragma unroll
            for (int j4 = 0; j4 < 4; ++j4) {
                const float4 kv = *(const float4*)&Kt[kk][dg * 16 + 4 * j4];
                acc = fmaf(q[4 * j4 + 0], kv.x, acc);
                acc = fmaf(q[4 * j4 + 1], kv.y, acc);
                acc = fmaf(q[4 * j4 + 2], kv.z, acc);
                acc = fmaf(q[4 * j4 + 3], kv.w, acc);
            }
            // combine the 4 dim-group partials (lanes dg=0..3 of this row)
            acc += __shfl_xor(acc, 1);
            acc += __shfl_xor(acc, 2);
            s[kk] = acc;
        }

        float mc = s[0];
#pragma unroll
        for (int kk = 1; kk < 32; ++kk) mc = fmaxf(mc, s[kk]);
        const float mnew = fmaxf(mrun, mc);
        const float rs   = exp2f(mrun - mnew);   // first iter: exp2(-inf) = 0
        lsum *= rs;
#pragma unroll
        for (int j = 0; j < 16; ++j) o[j] *= rs;

#pragma unroll
        for (int kk = 0; kk < 32; ++kk) {
            const float p = exp2f(s[kk] - mnew);
            lsum += p;
#pragma unroll
            for (int j4 = 0; j4 < 4; ++j4) {
                const float4 vv = *(const float4*)&Vt[kk][dg * 16 + 4 * j4];
                o[4 * j4 + 0] = fmaf(p, vv.x, o[4 * j4 + 0]);
                o[4 * j4 + 1] = fmaf(p, vv.y, o[4 * j4 + 1]);
                o[4 * j4 + 2] = fmaf(p, vv.z, o[4 * j4 + 2]);
                o[4 * j4 + 3] = fmaf(p, vv.w, o[4 * j4 + 3]);
            }
        }
        mrun = mnew;
    }

    const float inv = 1.0f / lsum;
    float* op = O + mrow * D_MODEL + h * DK + dg * 16;
#pragma unroll
    for (int j4 = 0; j4 < 4; ++j4) {
        float4 v4;
        v4.x = o[4 * j4 + 0] * inv;
        v4.y = o[4 * j4 + 1] * inv;
        v4.z = o[4 * j4 + 2] * inv;
        v4.w = o[4 * j4 + 3] * inv;
        *(float4*)(op + 4 * j4) = v4;
    }
}

// ---------------------------------------------------------------------------
// kernel_launch: x,Wq,bq,Wk,bk,Wv,bv,Wo,bo (fp32). Output fp32 [2,2048,1024].
// Workspace layout (fp32): Q | K | V | attn_out, 4 x 16 MB = 64 MB.
// All ws regions fully written before read -> poison-safe, replay-safe.
// ---------------------------------------------------------------------------
extern "C" void kernel_launch(void* const* d_in, const int* in_sizes, int n_in,
                              void* d_out, int out_size, void* d_ws, size_t ws_size,
                              hipStream_t stream)
{
    const float* x  = (const float*)d_in[0];
    const float* Wq = (const float*)d_in[1];
    const float* bq = (const float*)d_in[2];
    const float* Wk = (const float*)d_in[3];
    const float* bk = (const float*)d_in[4];
    const float* Wv = (const float*)d_in[5];
    const float* bv = (const float*)d_in[6];
    const float* Wo = (const float*)d_in[7];
    const float* bo = (const float*)d_in[8];

    float* out = (float*)d_out;
    float* ws  = (float*)d_ws;

    const size_t mat = (size_t)M_TOTAL * D_MODEL;   // 4096*1024
    float* Qw = ws;
    float* Kw = ws + mat;
    float* Vw = ws + 2 * mat;
    float* Aw = ws + 3 * mat;

    // 1) Q/K/V projections (fused via grid.z)
    qkv_gemm<<<dim3(16, 32, 3), 256, 0, stream>>>(x, Wq, bq, Wk, bk, Wv, bv, Qw, Kw, Vw);

    // 2) flash attention
    attn_kernel<<<dim3(SEQ / 64, BATCH * NHEADS), 256, 0, stream>>>(Qw, Kw, Vw, Aw);

    // 3) output projection
    oproj_gemm<<<dim3(16, 32), 256, 0, stream>>>(Aw, Wo, bo, out);
}

// Round 2
// 525.324 us; speedup vs baseline: 2.3196x; 2.3196x over previous
//
#include <hip/hip_runtime.h>
#include <hip/hip_bf16.h>
#include <cstdint>
#include <math.h>

#define D_MODEL 1024
#define NHEADS  16
#define DK      64
#define BATCH   2
#define SEQ     2048
#define M_TOTAL (BATCH*SEQ)   // 4096 rows

using f32x4 = __attribute__((ext_vector_type(4))) float;
using s16x8 = __attribute__((ext_vector_type(8))) short;

// ---------------------------------------------------------------------------
// fp32 GEMM body: C[M_TOTAL][1024] = A @ B + bias. BM=128,BN=64,BK=16,
// 256 thr, 8x4 micro-kernel. Optional bf16 output packing (for Q/K/V).
// ---------------------------------------------------------------------------
template<bool BF16OUT>
__device__ __forceinline__ void gemm_body(const float* __restrict__ A,
                                          const float* __restrict__ B,
                                          const float* __restrict__ bias,
                                          void* __restrict__ Cout)
{
    __shared__ float As[16][132];
    __shared__ float Bs[16][68];

    const int t  = threadIdx.x;
    const int tx = t & 15;
    const int ty = t >> 4;
    const int m0 = blockIdx.y * 128;
    const int n0 = blockIdx.x * 64;

    float acc[8][4];
#pragma unroll
    for (int i = 0; i < 8; ++i)
#pragma unroll
        for (int j = 0; j < 4; ++j) acc[i][j] = 0.f;

    const int arow = t >> 2;
    const int ac4  = (t & 3) * 4;
    const int br   = t >> 4;
    const int bc4  = (t & 15) * 4;

    for (int k0 = 0; k0 < 1024; k0 += 16) {
        const float4 av0 = *(const float4*)(A + (size_t)(m0 + arow     ) * 1024 + k0 + ac4);
        const float4 av1 = *(const float4*)(A + (size_t)(m0 + arow + 64) * 1024 + k0 + ac4);
        const float4 bv  = *(const float4*)(B + (size_t)(k0 + br) * 1024 + n0 + bc4);

        __syncthreads();
        As[ac4 + 0][arow]      = av0.x;
        As[ac4 + 1][arow]      = av0.y;
        As[ac4 + 2][arow]      = av0.z;
        As[ac4 + 3][arow]      = av0.w;
        As[ac4 + 0][arow + 64] = av1.x;
        As[ac4 + 1][arow + 64] = av1.y;
        As[ac4 + 2][arow + 64] = av1.z;
        As[ac4 + 3][arow + 64] = av1.w;
        *(float4*)&Bs[br][bc4] = bv;
        __syncthreads();

#pragma unroll
        for (int kk = 0; kk < 16; ++kk) {
            const float4 a0 = *(const float4*)&As[kk][8 * ty];
            const float4 a1 = *(const float4*)&As[kk][8 * ty + 4];
            const float4 b4 = *(const float4*)&Bs[kk][4 * tx];
            const float a[8]  = {a0.x, a0.y, a0.z, a0.w, a1.x, a1.y, a1.z, a1.w};
            const float bb[4] = {b4.x, b4.y, b4.z, b4.w};
#pragma unroll
            for (int i = 0; i < 8; ++i)
#pragma unroll
                for (int j = 0; j < 4; ++j)
                    acc[i][j] = fmaf(a[i], bb[j], acc[i][j]);
        }
    }

    const float4 bb4 = *(const float4*)(bias + n0 + tx * 4);
#pragma unroll
    for (int i = 0; i < 8; ++i) {
        float v[4];
        v[0] = acc[i][0] + bb4.x;
        v[1] = acc[i][1] + bb4.y;
        v[2] = acc[i][2] + bb4.z;
        v[3] = acc[i][3] + bb4.w;
        if constexpr (BF16OUT) {
            ushort4 pk;
            __hip_bfloat16 h0 = __float2bfloat16(v[0]);
            __hip_bfloat16 h1 = __float2bfloat16(v[1]);
            __hip_bfloat16 h2 = __float2bfloat16(v[2]);
            __hip_bfloat16 h3 = __float2bfloat16(v[3]);
            pk.x = *(unsigned short*)&h0;
            pk.y = *(unsigned short*)&h1;
            pk.z = *(unsigned short*)&h2;
            pk.w = *(unsigned short*)&h3;
            *(ushort4*)((unsigned short*)Cout + (size_t)(m0 + ty * 8 + i) * 1024 + n0 + tx * 4) = pk;
        } else {
            float4 c; c.x = v[0]; c.y = v[1]; c.z = v[2]; c.w = v[3];
            *(float4*)((float*)Cout + (size_t)(m0 + ty * 8 + i) * 1024 + n0 + tx * 4) = c;
        }
    }
}

__global__ __launch_bounds__(256) void qkv_gemm(const float* __restrict__ x,
                                                const float* __restrict__ Wq, const float* __restrict__ bq,
                                                const float* __restrict__ Wk, const float* __restrict__ bk,
                                                const float* __restrict__ Wv, const float* __restrict__ bv,
                                                unsigned short* __restrict__ Q,
                                                unsigned short* __restrict__ K,
                                                unsigned short* __restrict__ V)
{
    const float* B; const float* bias; unsigned short* C;
    if (blockIdx.z == 0)      { B = Wq; bias = bq; C = Q; }
    else if (blockIdx.z == 1) { B = Wk; bias = bk; C = K; }
    else                      { B = Wv; bias = bv; C = V; }
    gemm_body<true>(x, B, bias, C);
}

__global__ __launch_bounds__(256) void oproj_gemm(const float* __restrict__ A,
                                                  const float* __restrict__ Wo,
                                                  const float* __restrict__ bo,
                                                  float* __restrict__ C)
{
    gemm_body<false>(A, Wo, bo, C);
}

// ---------------------------------------------------------------------------
// MFMA flash attention, bf16 inputs, fp32 accumulate/output.
// Block: 256 thr = 4 waves; wave owns 16 q-rows; block = 64 q-rows of one
// (b,h). Grid (32, 32). KV tile = 64 keys staged in LDS per block:
//   Klds  [64 key][64 d]  bf16, byte ^= ((key&7)<<4) class-swizzle
//   Vtlds [64 d][64 key]  bf16 (transposed), same swizzle on key-classes
// Swapped QK^T: S^T = mfma(A=K, B=Q^T) -> lane holds 16 scores for its own
// q (= lane&15); softmax is 2 shfl_xor steps. P round-trips a per-wave 2KB
// swizzled LDS buffer (u32 writes -> b128 A-frag reads) for PV.
// ---------------------------------------------------------------------------
__global__ __launch_bounds__(256) void attn_mfma(const unsigned short* __restrict__ Qb,
                                                 const unsigned short* __restrict__ Kb,
                                                 const unsigned short* __restrict__ Vb,
                                                 float* __restrict__ O)
{
    __shared__ unsigned short Klds [64 * 64];      // 8 KB
    __shared__ unsigned short Vtlds[64 * 64];      // 8 KB
    __shared__ unsigned short Plds [4][16 * 64];   // 4 x 2 KB (per wave)

    const int t    = threadIdx.x;
    const int wid  = t >> 6;
    const int lane = t & 63;
    const int g    = lane >> 4;     // 0..3
    const int ln   = lane & 15;     // 0..15

    const int bh = blockIdx.y;
    const int b  = bh >> 4;
    const int h  = bh & 15;
    const int qbase = blockIdx.x * 64 + wid * 16;          // q offset in sequence
    const size_t qrow  = (size_t)(b * SEQ + qbase + ln);   // this lane's q row
    const size_t kvrow0 = (size_t)(b * SEQ);

    const float csc = 0.125f * 1.44269504088896341f;  // (1/sqrt(Dk)) * log2(e)

    // Q fragments (B operand): lane holds Q[q=ln][dims 8g+32ks .. +7]
    s16x8 qf[2];
    {
        const unsigned short* qp = Qb + qrow * D_MODEL + h * DK + 8 * g;
        qf[0] = *(const s16x8*)(qp);
        qf[1] = *(const s16x8*)(qp + 32);
    }

    f32x4 of[4];   // O accum: [ntile]; lane: row q=4g+j, col d=16n+ln
#pragma unroll
    for (int n = 0; n < 4; ++n)
#pragma unroll
        for (int j = 0; j < 4; ++j) of[n][j] = 0.f;

    float mrun = -INFINITY, lsum = 0.f;

    char* const pb = (char*)&Plds[wid][0];

    for (int kt = 0; kt < SEQ / 64; ++kt) {
        const size_t kvb = kvrow0 + (size_t)kt * 64;
        __syncthreads();   // all waves done with previous K/V tiles
        // ---- stage K (coalesced b128 reads, swizzled b128 LDS writes) ----
        {
            const int key = t >> 3;          // 0..31
            const int c   = t & 7;           // 16B class (8 dims)
            const s16x8 v0 = *(const s16x8*)(Kb + (kvb + key     ) * D_MODEL + h * DK + 8 * c);
            const s16x8 v1 = *(const s16x8*)(Kb + (kvb + key + 32) * D_MODEL + h * DK + 8 * c);
            *(s16x8*)((char*)Klds + key * 128        + 16 * (c ^ (key & 7))) = v0;
            *(s16x8*)((char*)Klds + (key + 32) * 128 + 16 * (c ^ (key & 7))) = v1;
        }
        // ---- stage V^T (reg transpose; packed key-pair u32 writes) ----
        {
            const int k2 = 2 * (t & 31);     // even key
            const int d0 = 8 * (t >> 5);     // 0..56
            const s16x8 r0 = *(const s16x8*)(Vb + (kvb + k2    ) * D_MODEL + h * DK + d0);
            const s16x8 r1 = *(const s16x8*)(Vb + (kvb + k2 + 1) * D_MODEL + h * DK + d0);
#pragma unroll
            for (int i = 0; i < 8; ++i) {
                const int d = d0 + i;
                const uint32_t val = (uint32_t)(unsigned short)r0[i] |
                                     ((uint32_t)(unsigned short)r1[i] << 16);
                *(uint32_t*)((char*)Vtlds + d * 128 + 16 * ((k2 >> 3) ^ (d & 7)) + (k2 & 7) * 2) = val;
            }
        }
        __syncthreads();

        // ---- scores: S^T = K * Q^T, 4 key-tiles x 2 k-steps ----
        f32x4 sc[4];
#pragma unroll
        for (int m = 0; m < 4; ++m)
#pragma unroll
            for (int j = 0; j < 4; ++j) sc[m][j] = 0.f;
#pragma unroll
        for (int ks = 0; ks < 2; ++ks)
#pragma unroll
            for (int m = 0; m < 4; ++m) {
                const int key = 16 * m + ln;
                const s16x8 ka = *(const s16x8*)((char*)Klds + key * 128 +
                                                 16 * ((4 * ks + g) ^ (key & 7)));
                sc[m] = __builtin_amdgcn_mfma_f32_16x16x32_bf16(ka, qf[ks], sc[m], 0, 0, 0);
            }

        // ---- online softmax (lane owns q = ln; scores for keys 16m+4g+j) ----
        float mc = sc[0][0];
#pragma unroll
        for (int m = 0; m < 4; ++m)
#pragma unroll
            for (int j = 0; j < 4; ++j) mc = fmaxf(mc, sc[m][j]);
        mc = fmaxf(mc, __shfl_xor(mc, 16));
        mc = fmaxf(mc, __shfl_xor(mc, 32));
        mc *= csc;
        const float mnew = fmaxf(mrun, mc);
        const float r    = exp2f(mrun - mnew);   // 0 on first tile
        float p[4][4];
        float ts = 0.f;
#pragma unroll
        for (int m = 0; m < 4; ++m)
#pragma unroll
            for (int j = 0; j < 4; ++j) {
                p[m][j] = exp2f(fmaf(sc[m][j], csc, -mnew));
                ts += p[m][j];
            }
        ts += __shfl_xor(ts, 16);
        ts += __shfl_xor(ts, 32);
        lsum = lsum * r + ts;
        mrun = mnew;

        // rescale O rows (row q = 4g+j gets r from lane with ln == 4g+j)
#pragma unroll
        for (int j = 0; j < 4; ++j) {
            const float rj = __shfl(r, 20 * g + j);
#pragma unroll
            for (int n = 0; n < 4; ++n) of[n][j] *= rj;
        }

        // ---- pack P (bf16) into per-wave swizzled LDS buffer ----
#pragma unroll
        for (int m = 0; m < 4; ++m)
#pragma unroll
            for (int hh = 0; hh < 2; ++hh) {
                const int key = 16 * m + 4 * g + 2 * hh;
                __hip_bfloat16 b0 = __float2bfloat16(p[m][2 * hh]);
                __hip_bfloat16 b1 = __float2bfloat16(p[m][2 * hh + 1]);
                const uint32_t val = (uint32_t)*(unsigned short*)&b0 |
                                     ((uint32_t)*(unsigned short*)&b1 << 16);
                *(uint32_t*)(pb + ln * 128 + 16 * ((key >> 3) ^ (ln & 7)) + (key & 7) * 2) = val;
            }

        // ---- PV: O += P * V ----
#pragma unroll
        for (int ks = 0; ks < 2; ++ks) {
            const s16x8 pa = *(const s16x8*)(pb + ln * 128 + 16 * ((4 * ks + g) ^ (ln & 7)));
#pragma unroll
            for (int n = 0; n < 4; ++n) {
                const int d = 16 * n + ln;
                const s16x8 vb = *(const s16x8*)((char*)Vtlds + d * 128 +
                                                 16 * ((4 * ks + g) ^ (d & 7)));
                of[n] = __builtin_amdgcn_mfma_f32_16x16x32_bf16(pa, vb, of[n], 0, 0, 0);
            }
        }
    }

    // ---- normalize + store (fp32) ----
    const float inv = 1.0f / lsum;
#pragma unroll
    for (int j = 0; j < 4; ++j) {
        const float ij = __shfl(inv, 20 * g + j);
        const size_t row = (size_t)(b * SEQ + qbase + 4 * g + j);
#pragma unroll
        for (int n = 0; n < 4; ++n)
            O[row * D_MODEL + h * DK + 16 * n + ln] = of[n][j] * ij;
    }
}

// ---------------------------------------------------------------------------
// ws layout: Qb|Kb|Vb bf16 (8MB each) then attn_out fp32 (16MB) = 40MB.
// All regions fully written before read -> poison/replay safe.
// ---------------------------------------------------------------------------
extern "C" void kernel_launch(void* const* d_in, const int* in_sizes, int n_in,
                              void* d_out, int out_size, void* d_ws, size_t ws_size,
                              hipStream_t stream)
{
    const float* x  = (const float*)d_in[0];
    const float* Wq = (const float*)d_in[1];
    const float* bq = (const float*)d_in[2];
    const float* Wk = (const float*)d_in[3];
    const float* bk = (const float*)d_in[4];
    const float* Wv = (const float*)d_in[5];
    const float* bv = (const float*)d_in[6];
    const float* Wo = (const float*)d_in[7];
    const float* bo = (const float*)d_in[8];

    float* out = (float*)d_out;

    const size_t mat = (size_t)M_TOTAL * D_MODEL;   // 4096*1024
    unsigned short* Qb = (unsigned short*)d_ws;
    unsigned short* Kb = Qb + mat;
    unsigned short* Vb = Kb + mat;
    float*          Aw = (float*)(Vb + mat);

    // 1) Q/K/V projections (fp32 compute, bf16 outputs)
    qkv_gemm<<<dim3(16, 32, 3), 256, 0, stream>>>(x, Wq, bq, Wk, bk, Wv, bv, Qb, Kb, Vb);

    // 2) MFMA flash attention (bf16 in, fp32 out)
    attn_mfma<<<dim3(SEQ / 64, BATCH * NHEADS), 256, 0, stream>>>(Qb, Kb, Vb, Aw);

    // 3) output projection (fp32)
    oproj_gemm<<<dim3(16, 32), 256, 0, stream>>>(Aw, Wo, bo, out);
}

// Round 3
// 167.002 us; speedup vs baseline: 7.2965x; 3.1456x over previous
//
#include <hip/hip_runtime.h>
#include <hip/hip_bf16.h>
#include <cstdint>
#include <math.h>

#define D_MODEL 1024
#define NHEADS  16
#define DK      64
#define BATCH   2
#define SEQ     2048
#define M_TOTAL (BATCH*SEQ)   // 4096 rows

using f32x4 = __attribute__((ext_vector_type(4))) float;
using s16x8 = __attribute__((ext_vector_type(8))) short;

__device__ __forceinline__ unsigned short bf16r(float f) {
    __hip_bfloat16 h = __float2bfloat16(f);
    return *(unsigned short*)&h;
}

// ---------------------------------------------------------------------------
// fp32 -> bf16 elementwise (x). 8 elems/thread, vectorized.
// ---------------------------------------------------------------------------
__global__ __launch_bounds__(256) void conv_x(const float* __restrict__ x,
                                              unsigned short* __restrict__ xb)
{
    const size_t i = ((size_t)blockIdx.x * 256 + threadIdx.x) * 8;
    const float4 a = *(const float4*)(x + i);
    const float4 b = *(const float4*)(x + i + 4);
    ushort4 r0, r1;
    r0.x = bf16r(a.x); r0.y = bf16r(a.y); r0.z = bf16r(a.z); r0.w = bf16r(a.w);
    r1.x = bf16r(b.x); r1.y = bf16r(b.y); r1.z = bf16r(b.z); r1.w = bf16r(b.w);
    *(ushort4*)(xb + i)     = r0;
    *(ushort4*)(xb + i + 4) = r1;
}

// ---------------------------------------------------------------------------
// Transpose + convert: T[n][k] = bf16(W[k][n]), 1024x1024, 32x32 LDS tiles.
// z selects which of the 4 weight matrices.
// ---------------------------------------------------------------------------
__global__ __launch_bounds__(256) void conv_wt(const float* __restrict__ W0, const float* __restrict__ W1,
                                               const float* __restrict__ W2, const float* __restrict__ W3,
                                               unsigned short* __restrict__ T0, unsigned short* __restrict__ T1,
                                               unsigned short* __restrict__ T2, unsigned short* __restrict__ T3)
{
    const float* W; unsigned short* T;
    switch (blockIdx.z) {
        case 0: W = W0; T = T0; break;
        case 1: W = W1; T = T1; break;
        case 2: W = W2; T = T2; break;
        default: W = W3; T = T3; break;
    }
    __shared__ float tile[32][33];
    const int t  = threadIdx.x;
    const int r  = t >> 3;          // 0..31
    const int c4 = (t & 7) * 4;     // 0..28
    const int k0 = blockIdx.x * 32;
    const int n0 = blockIdx.y * 32;

    const float4 v = *(const float4*)(W + (size_t)(k0 + r) * 1024 + n0 + c4);
    tile[r][c4 + 0] = v.x; tile[r][c4 + 1] = v.y; tile[r][c4 + 2] = v.z; tile[r][c4 + 3] = v.w;
    __syncthreads();
    ushort4 o;
    o.x = bf16r(tile[c4 + 0][r]);
    o.y = bf16r(tile[c4 + 1][r]);
    o.z = bf16r(tile[c4 + 2][r]);
    o.w = bf16r(tile[c4 + 3][r]);
    *(ushort4*)(T + (size_t)(n0 + r) * 1024 + k0 + c4) = o;
}

// ---------------------------------------------------------------------------
// bf16 MFMA GEMM (m97 structure): C[M][1024] = A[M][1024] @ Bt^T + bias.
// A, Bt bf16 row-major with K contiguous (Bt = W^T). 128x128 tile, BK=64,
// 256 thr = 4 waves (2x2), 4x4 16x16x32 fragments/wave.
// Staging: global_load_lds width=16, linear LDS dest, inverse-swizzled global
// source (chunk ^= row&7); reads apply the same XOR -> near-conflict-free.
// ---------------------------------------------------------------------------
template<int OUT_BF16>
__device__ __forceinline__ void gemm_mfma_body(const unsigned short* __restrict__ A,
                                               const unsigned short* __restrict__ Bt,
                                               const float* __restrict__ bias,
                                               void* __restrict__ C)
{
    __shared__ unsigned short As[128 * 64];
    __shared__ unsigned short Bs[128 * 64];

    const int t    = threadIdx.x;
    const int w    = t >> 6;
    const int lane = t & 63;
    const int ln   = lane & 15;
    const int g    = lane >> 4;          // 0..3
    const int wr   = w >> 1, wc = w & 1;
    const int m0   = blockIdx.y * 128;
    const int n0   = blockIdx.x * 128;

    f32x4 acc[4][4];
#pragma unroll
    for (int mi = 0; mi < 4; ++mi)
#pragma unroll
        for (int ni = 0; ni < 4; ++ni)
#pragma unroll
            for (int j = 0; j < 4; ++j) acc[mi][ni][j] = 0.f;

    // staging source mapping: lane covers (row = w*32 + i*8 + (lane>>3),
    // chunk = (lane&7) ^ (lane>>3)) of the 128x64 tile; 16B per lane.
    const int lrow = lane >> 3;                 // 0..7
    const int lchk = (lane & 7) ^ lrow;         // inverse swizzle
    const unsigned short* Ag = A  + (size_t)(m0 + w * 32 + lrow) * 1024 + lchk * 8;
    const unsigned short* Bg = Bt + (size_t)(n0 + w * 32 + lrow) * 1024 + lchk * 8;

    for (int kt = 0; kt < 16; ++kt) {
        const int k0 = kt * 64;
#pragma unroll
        for (int i = 0; i < 4; ++i) {
            __builtin_amdgcn_global_load_lds(Ag + (size_t)i * 8 * 1024 + k0,
                                             &As[(w * 32 + i * 8) * 64], 16, 0, 0);
            __builtin_amdgcn_global_load_lds(Bg + (size_t)i * 8 * 1024 + k0,
                                             &Bs[(w * 32 + i * 8) * 64], 16, 0, 0);
        }
        __syncthreads();   // compiler drains vmcnt(0) here

#pragma unroll
        for (int ks = 0; ks < 2; ++ks) {
            s16x8 af[4], bf[4];
#pragma unroll
            for (int mi = 0; mi < 4; ++mi) {
                const int row = wr * 64 + mi * 16 + ln;
                af[mi] = *(const s16x8*)((const char*)As + row * 128 +
                                         (((ks * 4 + g) ^ (ln & 7)) * 16));
            }
#pragma unroll
            for (int ni = 0; ni < 4; ++ni) {
                const int row = wc * 64 + ni * 16 + ln;
                bf[ni] = *(const s16x8*)((const char*)Bs + row * 128 +
                                         (((ks * 4 + g) ^ (ln & 7)) * 16));
            }
#pragma unroll
            for (int mi = 0; mi < 4; ++mi)
#pragma unroll
                for (int ni = 0; ni < 4; ++ni)
                    acc[mi][ni] = __builtin_amdgcn_mfma_f32_16x16x32_bf16(
                        af[mi], bf[ni], acc[mi][ni], 0, 0, 0);
        }
        __syncthreads();   // before next stage overwrites
    }

    // epilogue: C/D layout col=lane&15, row=(lane>>4)*4+j
#pragma unroll
    for (int ni = 0; ni < 4; ++ni) {
        const int n = n0 + wc * 64 + ni * 16 + ln;
        const float bn = bias[n];
#pragma unroll
        for (int mi = 0; mi < 4; ++mi) {
            const int m = m0 + wr * 64 + mi * 16 + g * 4;
#pragma unroll
            for (int j = 0; j < 4; ++j) {
                const float v = acc[mi][ni][j] + bn;
                if constexpr (OUT_BF16)
                    ((unsigned short*)C)[(size_t)(m + j) * 1024 + n] = bf16r(v);
                else
                    ((float*)C)[(size_t)(m + j) * 1024 + n] = v;
            }
        }
    }
}

__global__ __launch_bounds__(256) void qkv_mfma(const unsigned short* __restrict__ xb,
                                                const unsigned short* __restrict__ Wqt, const float* __restrict__ bq,
                                                const unsigned short* __restrict__ Wkt, const float* __restrict__ bk,
                                                const unsigned short* __restrict__ Wvt, const float* __restrict__ bv,
                                                unsigned short* __restrict__ Q,
                                                unsigned short* __restrict__ K,
                                                unsigned short* __restrict__ V)
{
    const unsigned short* Bt; const float* bias; unsigned short* C;
    if (blockIdx.z == 0)      { Bt = Wqt; bias = bq; C = Q; }
    else if (blockIdx.z == 1) { Bt = Wkt; bias = bk; C = K; }
    else                      { Bt = Wvt; bias = bv; C = V; }
    gemm_mfma_body<1>(xb, Bt, bias, C);
}

__global__ __launch_bounds__(256) void oproj_mfma(const unsigned short* __restrict__ Ab,
                                                  const unsigned short* __restrict__ Wot,
                                                  const float* __restrict__ bo,
                                                  float* __restrict__ C)
{
    gemm_mfma_body<0>(Ab, Wot, bo, C);
}

// ---------------------------------------------------------------------------
// MFMA flash attention (unchanged from round 2 except bf16 output).
// ---------------------------------------------------------------------------
__global__ __launch_bounds__(256) void attn_mfma(const unsigned short* __restrict__ Qb,
                                                 const unsigned short* __restrict__ Kb,
                                                 const unsigned short* __restrict__ Vb,
                                                 unsigned short* __restrict__ O)
{
    __shared__ unsigned short Klds [64 * 64];
    __shared__ unsigned short Vtlds[64 * 64];
    __shared__ unsigned short Plds [4][16 * 64];

    const int t    = threadIdx.x;
    const int wid  = t >> 6;
    const int lane = t & 63;
    const int g    = lane >> 4;
    const int ln   = lane & 15;

    const int bh = blockIdx.y;
    const int b  = bh >> 4;
    const int h  = bh & 15;
    const int qbase = blockIdx.x * 64 + wid * 16;
    const size_t qrow   = (size_t)(b * SEQ + qbase + ln);
    const size_t kvrow0 = (size_t)(b * SEQ);

    const float csc = 0.125f * 1.44269504088896341f;

    s16x8 qf[2];
    {
        const unsigned short* qp = Qb + qrow * D_MODEL + h * DK + 8 * g;
        qf[0] = *(const s16x8*)(qp);
        qf[1] = *(const s16x8*)(qp + 32);
    }

    f32x4 of[4];
#pragma unroll
    for (int n = 0; n < 4; ++n)
#pragma unroll
        for (int j = 0; j < 4; ++j) of[n][j] = 0.f;

    float mrun = -INFINITY, lsum = 0.f;
    char* const pb = (char*)&Plds[wid][0];

    for (int kt = 0; kt < SEQ / 64; ++kt) {
        const size_t kvb = kvrow0 + (size_t)kt * 64;
        __syncthreads();
        {
            const int key = t >> 3;
            const int c   = t & 7;
            const s16x8 v0 = *(const s16x8*)(Kb + (kvb + key     ) * D_MODEL + h * DK + 8 * c);
            const s16x8 v1 = *(const s16x8*)(Kb + (kvb + key + 32) * D_MODEL + h * DK + 8 * c);
            *(s16x8*)((char*)Klds + key * 128        + 16 * (c ^ (key & 7))) = v0;
            *(s16x8*)((char*)Klds + (key + 32) * 128 + 16 * (c ^ (key & 7))) = v1;
        }
        {
            const int k2 = 2 * (t & 31);
            const int d0 = 8 * (t >> 5);
            const s16x8 r0 = *(const s16x8*)(Vb + (kvb + k2    ) * D_MODEL + h * DK + d0);
            const s16x8 r1 = *(const s16x8*)(Vb + (kvb + k2 + 1) * D_MODEL + h * DK + d0);
#pragma unroll
            for (int i = 0; i < 8; ++i) {
                const int d = d0 + i;
                const uint32_t val = (uint32_t)(unsigned short)r0[i] |
                                     ((uint32_t)(unsigned short)r1[i] << 16);
                *(uint32_t*)((char*)Vtlds + d * 128 + 16 * ((k2 >> 3) ^ (d & 7)) + (k2 & 7) * 2) = val;
            }
        }
        __syncthreads();

        f32x4 sc[4];
#pragma unroll
        for (int m = 0; m < 4; ++m)
#pragma unroll
            for (int j = 0; j < 4; ++j) sc[m][j] = 0.f;
#pragma unroll
        for (int ks = 0; ks < 2; ++ks)
#pragma unroll
            for (int m = 0; m < 4; ++m) {
                const int key = 16 * m + ln;
                const s16x8 ka = *(const s16x8*)((char*)Klds + key * 128 +
                                                 16 * ((4 * ks + g) ^ (key & 7)));
                sc[m] = __builtin_amdgcn_mfma_f32_16x16x32_bf16(ka, qf[ks], sc[m], 0, 0, 0);
            }

        float mc = sc[0][0];
#pragma unroll
        for (int m = 0; m < 4; ++m)
#pragma unroll
            for (int j = 0; j < 4; ++j) mc = fmaxf(mc, sc[m][j]);
        mc = fmaxf(mc, __shfl_xor(mc, 16));
        mc = fmaxf(mc, __shfl_xor(mc, 32));
        mc *= csc;
        const float mnew = fmaxf(mrun, mc);
        const float r    = exp2f(mrun - mnew);
        float p[4][4];
        float ts = 0.f;
#pragma unroll
        for (int m = 0; m < 4; ++m)
#pragma unroll
            for (int j = 0; j < 4; ++j) {
                p[m][j] = exp2f(fmaf(sc[m][j], csc, -mnew));
                ts += p[m][j];
            }
        ts += __shfl_xor(ts, 16);
        ts += __shfl_xor(ts, 32);
        lsum = lsum * r + ts;
        mrun = mnew;

#pragma unroll
        for (int j = 0; j < 4; ++j) {
            const float rj = __shfl(r, 20 * g + j);
#pragma unroll
            for (int n = 0; n < 4; ++n) of[n][j] *= rj;
        }

#pragma unroll
        for (int m = 0; m < 4; ++m)
#pragma unroll
            for (int hh = 0; hh < 2; ++hh) {
                const int key = 16 * m + 4 * g + 2 * hh;
                const uint32_t val = (uint32_t)bf16r(p[m][2 * hh]) |
                                     ((uint32_t)bf16r(p[m][2 * hh + 1]) << 16);
                *(uint32_t*)(pb + ln * 128 + 16 * ((key >> 3) ^ (ln & 7)) + (key & 7) * 2) = val;
            }

#pragma unroll
        for (int ks = 0; ks < 2; ++ks) {
            const s16x8 pa = *(const s16x8*)(pb + ln * 128 + 16 * ((4 * ks + g) ^ (ln & 7)));
#pragma unroll
            for (int n = 0; n < 4; ++n) {
                const int d = 16 * n + ln;
                const s16x8 vb = *(const s16x8*)((char*)Vtlds + d * 128 +
                                                 16 * ((4 * ks + g) ^ (d & 7)));
                of[n] = __builtin_amdgcn_mfma_f32_16x16x32_bf16(pa, vb, of[n], 0, 0, 0);
            }
        }
    }

    const float inv = 1.0f / lsum;
#pragma unroll
    for (int j = 0; j < 4; ++j) {
        const float ij = __shfl(inv, 20 * g + j);
        const size_t row = (size_t)(b * SEQ + qbase + 4 * g + j);
#pragma unroll
        for (int n = 0; n < 4; ++n)
            O[row * D_MODEL + h * DK + 16 * n + ln] = bf16r(of[n][j] * ij);
    }
}

// ---------------------------------------------------------------------------
// ws layout (bf16 unless noted):
//   xb 8MB | Wqt 2MB | Wkt 2MB | Wvt 2MB | Wot 2MB | Qb 8MB | Kb 8MB |
//   Vb 8MB | Ab 8MB  -> 48 MB. All fully written before read.
// ---------------------------------------------------------------------------
extern "C" void kernel_launch(void* const* d_in, const int* in_sizes, int n_in,
                              void* d_out, int out_size, void* d_ws, size_t ws_size,
                              hipStream_t stream)
{
    const float* x  = (const float*)d_in[0];
    const float* Wq = (const float*)d_in[1];
    const float* bq = (const float*)d_in[2];
    const float* Wk = (const float*)d_in[3];
    const float* bk = (const float*)d_in[4];
    const float* Wv = (const float*)d_in[5];
    const float* bv = (const float*)d_in[6];
    const float* Wo = (const float*)d_in[7];
    const float* bo = (const float*)d_in[8];

    float* out = (float*)d_out;

    const size_t mat  = (size_t)M_TOTAL * D_MODEL;   // 4096*1024
    const size_t wmat = (size_t)D_MODEL * D_MODEL;   // 1024*1024
    unsigned short* xb  = (unsigned short*)d_ws;
    unsigned short* Wqt = xb  + mat;
    unsigned short* Wkt = Wqt + wmat;
    unsigned short* Wvt = Wkt + wmat;
    unsigned short* Wot = Wvt + wmat;
    unsigned short* Qb  = Wot + wmat;
    unsigned short* Kb  = Qb  + mat;
    unsigned short* Vb  = Kb  + mat;
    unsigned short* Ab  = Vb  + mat;

    // 0) conversions
    conv_x<<<dim3(2048), 256, 0, stream>>>(x, xb);
    conv_wt<<<dim3(32, 32, 4), 256, 0, stream>>>(Wq, Wk, Wv, Wo, Wqt, Wkt, Wvt, Wot);

    // 1) Q/K/V projections (bf16 MFMA)
    qkv_mfma<<<dim3(8, 32, 3), 256, 0, stream>>>(xb, Wqt, bq, Wkt, bk, Wvt, bv, Qb, Kb, Vb);

    // 2) flash attention (bf16 MFMA)
    attn_mfma<<<dim3(SEQ / 64, BATCH * NHEADS), 256, 0, stream>>>(Qb, Kb, Vb, Ab);

    // 3) output projection (bf16 MFMA, fp32 out)
    oproj_mfma<<<dim3(8, 32), 256, 0, stream>>>(Ab, Wot, bo, out);
}

// Round 5
// 155.503 us; speedup vs baseline: 7.8360x; 1.0739x over previous
//
#include <hip/hip_runtime.h>
#include <hip/hip_bf16.h>
#include <cstdint>
#include <math.h>

#define D_MODEL 1024
#define NHEADS  16
#define DK      64
#define BATCH   2
#define SEQ     2048
#define M_TOTAL (BATCH*SEQ)   // 4096 rows

using f32x4  = __attribute__((ext_vector_type(4)))  float;
using f32x16 = __attribute__((ext_vector_type(16))) float;
using s16x8  = __attribute__((ext_vector_type(8)))  short;

#define CSC (0.125f * 1.44269504088896341f)   // (1/sqrt(Dk)) * log2(e)

__device__ __forceinline__ unsigned short bf16r(float f) {
    __hip_bfloat16 h = __float2bfloat16(f);
    return *(unsigned short*)&h;
}
__device__ __forceinline__ uint32_t packbf(float lo, float hi) {
    return (uint32_t)bf16r(lo) | ((uint32_t)bf16r(hi) << 16);
}

// ---------------------------------------------------------------------------
// fp32 -> bf16 elementwise (x). 8 elems/thread, vectorized.
// ---------------------------------------------------------------------------
__global__ __launch_bounds__(256) void conv_x(const float* __restrict__ x,
                                              unsigned short* __restrict__ xb)
{
    const size_t i = ((size_t)blockIdx.x * 256 + threadIdx.x) * 8;
    const float4 a = *(const float4*)(x + i);
    const float4 b = *(const float4*)(x + i + 4);
    ushort4 r0, r1;
    r0.x = bf16r(a.x); r0.y = bf16r(a.y); r0.z = bf16r(a.z); r0.w = bf16r(a.w);
    r1.x = bf16r(b.x); r1.y = bf16r(b.y); r1.z = bf16r(b.z); r1.w = bf16r(b.w);
    *(ushort4*)(xb + i)     = r0;
    *(ushort4*)(xb + i + 4) = r1;
}

// ---------------------------------------------------------------------------
// Transpose + convert: T[n][k] = bf16(W[k][n]), 1024x1024, 32x32 LDS tiles.
// ---------------------------------------------------------------------------
__global__ __launch_bounds__(256) void conv_wt(const float* __restrict__ W0, const float* __restrict__ W1,
                                               const float* __restrict__ W2, const float* __restrict__ W3,
                                               unsigned short* __restrict__ T0, unsigned short* __restrict__ T1,
                                               unsigned short* __restrict__ T2, unsigned short* __restrict__ T3)
{
    const float* W; unsigned short* T;
    switch (blockIdx.z) {
        case 0: W = W0; T = T0; break;
        case 1: W = W1; T = T1; break;
        case 2: W = W2; T = T2; break;
        default: W = W3; T = T3; break;
    }
    __shared__ float tile[32][33];
    const int t  = threadIdx.x;
    const int r  = t >> 3;
    const int c4 = (t & 7) * 4;
    const int k0 = blockIdx.x * 32;
    const int n0 = blockIdx.y * 32;

    const float4 v = *(const float4*)(W + (size_t)(k0 + r) * 1024 + n0 + c4);
    tile[r][c4 + 0] = v.x; tile[r][c4 + 1] = v.y; tile[r][c4 + 2] = v.z; tile[r][c4 + 3] = v.w;
    __syncthreads();
    ushort4 o;
    o.x = bf16r(tile[c4 + 0][r]);
    o.y = bf16r(tile[c4 + 1][r]);
    o.z = bf16r(tile[c4 + 2][r]);
    o.w = bf16r(tile[c4 + 3][r]);
    *(ushort4*)(T + (size_t)(n0 + r) * 1024 + k0 + c4) = o;
}

// ---------------------------------------------------------------------------
// bf16 MFMA GEMM (m97 structure), optional output scale (Q pre-scale by csc).
// ---------------------------------------------------------------------------
template<int OUT_BF16>
__device__ __forceinline__ void gemm_mfma_body(const unsigned short* __restrict__ A,
                                               const unsigned short* __restrict__ Bt,
                                               const float* __restrict__ bias,
                                               void* __restrict__ C,
                                               float oscale)
{
    __shared__ unsigned short As[128 * 64];
    __shared__ unsigned short Bs[128 * 64];

    const int t    = threadIdx.x;
    const int w    = t >> 6;
    const int lane = t & 63;
    const int ln   = lane & 15;
    const int g    = lane >> 4;
    const int wr   = w >> 1, wc = w & 1;
    const int m0   = blockIdx.y * 128;
    const int n0   = blockIdx.x * 128;

    f32x4 acc[4][4];
#pragma unroll
    for (int mi = 0; mi < 4; ++mi)
#pragma unroll
        for (int ni = 0; ni < 4; ++ni)
#pragma unroll
            for (int j = 0; j < 4; ++j) acc[mi][ni][j] = 0.f;

    const int lrow = lane >> 3;
    const int lchk = (lane & 7) ^ lrow;
    const unsigned short* Ag = A  + (size_t)(m0 + w * 32 + lrow) * 1024 + lchk * 8;
    const unsigned short* Bg = Bt + (size_t)(n0 + w * 32 + lrow) * 1024 + lchk * 8;

    for (int kt = 0; kt < 16; ++kt) {
        const int k0 = kt * 64;
#pragma unroll
        for (int i = 0; i < 4; ++i) {
            __builtin_amdgcn_global_load_lds(Ag + (size_t)i * 8 * 1024 + k0,
                                             &As[(w * 32 + i * 8) * 64], 16, 0, 0);
            __builtin_amdgcn_global_load_lds(Bg + (size_t)i * 8 * 1024 + k0,
                                             &Bs[(w * 32 + i * 8) * 64], 16, 0, 0);
        }
        __syncthreads();

#pragma unroll
        for (int ks = 0; ks < 2; ++ks) {
            s16x8 af[4], bf[4];
#pragma unroll
            for (int mi = 0; mi < 4; ++mi) {
                const int row = wr * 64 + mi * 16 + ln;
                af[mi] = *(const s16x8*)((const char*)As + row * 128 +
                                         (((ks * 4 + g) ^ (ln & 7)) * 16));
            }
#pragma unroll
            for (int ni = 0; ni < 4; ++ni) {
                const int row = wc * 64 + ni * 16 + ln;
                bf[ni] = *(const s16x8*)((const char*)Bs + row * 128 +
                                         (((ks * 4 + g) ^ (ln & 7)) * 16));
            }
#pragma unroll
            for (int mi = 0; mi < 4; ++mi)
#pragma unroll
                for (int ni = 0; ni < 4; ++ni)
                    acc[mi][ni] = __builtin_amdgcn_mfma_f32_16x16x32_bf16(
                        af[mi], bf[ni], acc[mi][ni], 0, 0, 0);
        }
        __syncthreads();
    }

#pragma unroll
    for (int ni = 0; ni < 4; ++ni) {
        const int n = n0 + wc * 64 + ni * 16 + ln;
        const float bn = bias[n];
#pragma unroll
        for (int mi = 0; mi < 4; ++mi) {
            const int m = m0 + wr * 64 + mi * 16 + g * 4;
#pragma unroll
            for (int j = 0; j < 4; ++j) {
                const float v = (acc[mi][ni][j] + bn) * oscale;
                if constexpr (OUT_BF16)
                    ((unsigned short*)C)[(size_t)(m + j) * 1024 + n] = bf16r(v);
                else
                    ((float*)C)[(size_t)(m + j) * 1024 + n] = v;
            }
        }
    }
}

__global__ __launch_bounds__(256) void qkv_mfma(const unsigned short* __restrict__ xb,
                                                const unsigned short* __restrict__ Wqt, const float* __restrict__ bq,
                                                const unsigned short* __restrict__ Wkt, const float* __restrict__ bk,
                                                const unsigned short* __restrict__ Wvt, const float* __restrict__ bv,
                                                unsigned short* __restrict__ Q,
                                                unsigned short* __restrict__ K,
                                                unsigned short* __restrict__ V)
{
    const unsigned short* Bt; const float* bias; unsigned short* C; float sc;
    if (blockIdx.z == 0)      { Bt = Wqt; bias = bq; C = Q; sc = CSC; }   // pre-scale Q
    else if (blockIdx.z == 1) { Bt = Wkt; bias = bk; C = K; sc = 1.0f; }
    else                      { Bt = Wvt; bias = bv; C = V; sc = 1.0f; }
    gemm_mfma_body<1>(xb, Bt, bias, C, sc);
}

__global__ __launch_bounds__(256) void oproj_mfma(const unsigned short* __restrict__ Ab,
                                                  const unsigned short* __restrict__ Wot,
                                                  const float* __restrict__ bo,
                                                  float* __restrict__ C)
{
    gemm_mfma_body<0>(Ab, Wot, bo, C, 1.0f);
}

// ---------------------------------------------------------------------------
// Flash attention on mfma_f32_32x32x16_bf16, lane-local softmax/O.
// Block: 256 thr = 4 waves x 32 q-rows = 128 q of one (b,h). Grid (16, 32).
//   QK^T: S^T[64k x 32q] = K·Q^T (A=K from LDS, B=Q regs) -> lane q=l&31
//     holds keys crow(r,hi)=(r&3)+8(r>>2)+4hi (+16/tile-half, +32/s1)
//   softmax: row-max/sum via __shfl_xor(·,32); defer-max THR=8
//   P pack: bf16 pair-pack + __shfl_xor(32) + cndmask slot select ->
//     B-frag slot (hi,j) holds key 16ks+8hi+j (verified against crow map)
//   PV: O^T[64d x 32q] += V^T·P^T -> O accum lane-local
// All cross-lane movement uses session-verified primitives only.
// ---------------------------------------------------------------------------
__global__ __launch_bounds__(256, 2) void attn_mfma(const unsigned short* __restrict__ Qb,
                                                    const unsigned short* __restrict__ Kb,
                                                    const unsigned short* __restrict__ Vb,
                                                    unsigned short* __restrict__ O)
{
    __shared__ unsigned short Klds [64 * 64];   // [key][d], chunk ^= key&7
    __shared__ unsigned short Vtlds[64 * 64];   // [d][key], chunk ^= d&7

    const int t   = threadIdx.x;
    const int wid = t >> 6;
    const int l   = t & 63;
    const int q32 = l & 31;
    const int hi  = l >> 5;

    const int bh = blockIdx.y;
    const int b  = bh >> 4;
    const int h  = bh & 15;
    const int qbase = blockIdx.x * 128 + wid * 32;
    const size_t qrow = (size_t)(b * SEQ + qbase + q32);
    const size_t kv0  = (size_t)(b * SEQ);

    // Q resident (B-frags): qf[ks] = Q[qrow][d = 16ks + 8hi .. +7]
    s16x8 qf[4];
    {
        const unsigned short* qp = Qb + qrow * D_MODEL + h * DK + 8 * hi;
        qf[0] = *(const s16x8*)(qp);
        qf[1] = *(const s16x8*)(qp + 16);
        qf[2] = *(const s16x8*)(qp + 32);
        qf[3] = *(const s16x8*)(qp + 48);
    }

    f32x16 ot0, ot1;   // O^T accum: d = crow(r,hi) + 32*{0,1}, col q = q32
#pragma unroll
    for (int i = 0; i < 16; ++i) { ot0[i] = 0.f; ot1[i] = 0.f; }
    float mrun = -INFINITY, lsum = 0.f;

    // staging mappings (block-wide, 256 threads, 64 keys x 64 d)
    const int skey = t >> 3;
    const int sc8  = t & 7;
    const int vk2  = 2 * (t & 31);
    const int vd0  = 8 * (t >> 5);
    const unsigned short* Kg = Kb + (kv0 + skey) * D_MODEL + h * DK + 8 * sc8;
    const unsigned short* Vg = Vb + (kv0 + vk2) * D_MODEL + h * DK + vd0;
    char* const kw0 = (char*)Klds + skey * 128        + 16 * (sc8 ^ (skey & 7));
    char* const kw1 = (char*)Klds + (skey + 32) * 128 + 16 * (sc8 ^ (skey & 7));

    s16x8 kr0, kr1, vr0, vr1;

    auto write_stage = [&]() {
        *(s16x8*)kw0 = kr0;
        *(s16x8*)kw1 = kr1;
#pragma unroll
        for (int i = 0; i < 8; ++i) {
            const int d = vd0 + i;
            const uint32_t val = (uint32_t)(unsigned short)vr0[i] |
                                 ((uint32_t)(unsigned short)vr1[i] << 16);
            *(uint32_t*)((char*)Vtlds + d * 128 + 16 * ((vk2 >> 3) ^ (d & 7)) + (vk2 & 7) * 2) = val;
        }
    };

    // prologue: stage tile 0
    kr0 = *(const s16x8*)(Kg);
    kr1 = *(const s16x8*)(Kg + (size_t)32 * D_MODEL);
    vr0 = *(const s16x8*)(Vg);
    vr1 = *(const s16x8*)(Vg + D_MODEL);
    write_stage();
    __syncthreads();

    for (int kt = 0; kt < SEQ / 64; ++kt) {
        // issue next tile's global loads (consumed after barrier 1)
        if (kt < SEQ / 64 - 1) {
            const size_t off = (size_t)(kt + 1) * 64 * D_MODEL;
            kr0 = *(const s16x8*)(Kg + off);
            kr1 = *(const s16x8*)(Kg + off + (size_t)32 * D_MODEL);
            vr0 = *(const s16x8*)(Vg + off);
            vr1 = *(const s16x8*)(Vg + off + D_MODEL);
        }

        // ---- QK^T ----
        f32x16 s0, s1;
#pragma unroll
        for (int i = 0; i < 16; ++i) { s0[i] = 0.f; s1[i] = 0.f; }
#pragma unroll
        for (int ks = 0; ks < 4; ++ks) {
            const int c = hi + 2 * ks;
            const s16x8 a0 = *(const s16x8*)((char*)Klds + q32 * 128 +
                                             16 * (c ^ (q32 & 7)));
            const s16x8 a1 = *(const s16x8*)((char*)Klds + (q32 + 32) * 128 +
                                             16 * (c ^ (q32 & 7)));
            s0 = __builtin_amdgcn_mfma_f32_32x32x16_bf16(a0, qf[ks], s0, 0, 0, 0);
            s1 = __builtin_amdgcn_mfma_f32_32x32x16_bf16(a1, qf[ks], s1, 0, 0, 0);
        }

        // ---- online softmax (scores already in exp2 domain) ----
        float mc = s0[0];
#pragma unroll
        for (int i = 1; i < 16; ++i) mc = fmaxf(mc, s0[i]);
#pragma unroll
        for (int i = 0; i < 16; ++i) mc = fmaxf(mc, s1[i]);
        mc = fmaxf(mc, __shfl_xor(mc, 32));   // full 64-key row max

        if (!__all(mc - mrun <= 8.0f)) {      // defer-max: rescale on growth only
            const float mnew = fmaxf(mrun, mc);
            const float r = exp2f(mrun - mnew);
            lsum *= r;
#pragma unroll
            for (int i = 0; i < 16; ++i) { ot0[i] *= r; ot1[i] *= r; }
            mrun = mnew;
        }

        float ls = 0.f;
#pragma unroll
        for (int i = 0; i < 16; ++i) {
            s0[i] = exp2f(s0[i] - mrun); ls += s0[i];
            s1[i] = exp2f(s1[i] - mrun); ls += s1[i];
        }
        lsum += ls;

        // ---- pack P -> PV B-frags (verified primitives only) ----
        // W[j] = own keys (crow(2j,hi), crow(2j+1,hi)); Y[j] = partner's W[j].
        // Slot map: B-frag slot (hi,j) needs key 16ks+8hi+j:
        //   pf[0]: hi=0 {W0,W1,Y0,Y1} | hi=1 {Y2,Y3,W2,W3}
        //   pf[1]: hi=0 {W4,W5,Y4,Y5} | hi=1 {Y6,Y7,W6,W7}   (s1 -> pf[2],pf[3])
        s16x8 pf[4];
#pragma unroll
        for (int half = 0; half < 2; ++half) {
            const f32x16& sv = half ? s1 : s0;
            uint32_t W[8], Y[8];
#pragma unroll
            for (int j = 0; j < 8; ++j) W[j] = packbf(sv[2 * j], sv[2 * j + 1]);
#pragma unroll
            for (int j = 0; j < 8; ++j) Y[j] = __shfl_xor(W[j], 32);
            union { uint32_t u[4]; s16x8 v; } F0, F1;
            F0.u[0] = hi ? Y[2] : W[0];
            F0.u[1] = hi ? Y[3] : W[1];
            F0.u[2] = hi ? W[2] : Y[0];
            F0.u[3] = hi ? W[3] : Y[1];
            F1.u[0] = hi ? Y[6] : W[4];
            F1.u[1] = hi ? Y[7] : W[5];
            F1.u[2] = hi ? W[6] : Y[4];
            F1.u[3] = hi ? W[7] : Y[5];
            pf[2 * half]     = F0.v;
            pf[2 * half + 1] = F1.v;
        }

        // ---- PV: O^T += V^T · P^T ----
#pragma unroll
        for (int ks = 0; ks < 4; ++ks) {
            const int c = hi + 2 * ks;
            const s16x8 av0 = *(const s16x8*)((char*)Vtlds + q32 * 128 +
                                              16 * (c ^ (q32 & 7)));
            const s16x8 av1 = *(const s16x8*)((char*)Vtlds + (q32 + 32) * 128 +
                                              16 * (c ^ (q32 & 7)));
            ot0 = __builtin_amdgcn_mfma_f32_32x32x16_bf16(av0, pf[ks], ot0, 0, 0, 0);
            ot1 = __builtin_amdgcn_mfma_f32_32x32x16_bf16(av1, pf[ks], ot1, 0, 0, 0);
        }

        __syncthreads();                 // all waves done reading K/V LDS
        if (kt < SEQ / 64 - 1) write_stage();
        __syncthreads();                 // next tile visible
    }

    // ---- normalize + store bf16 (d = 8j + 4hi + i + 32*dtile) ----
    const float inv = 1.0f / (lsum + __shfl_xor(lsum, 32));
    unsigned short* op = O + qrow * D_MODEL + h * DK;
#pragma unroll
    for (int j = 0; j < 4; ++j) {
        ushort4 st0, st1;
        st0.x = bf16r(ot0[4 * j + 0] * inv);
        st0.y = bf16r(ot0[4 * j + 1] * inv);
        st0.z = bf16r(ot0[4 * j + 2] * inv);
        st0.w = bf16r(ot0[4 * j + 3] * inv);
        st1.x = bf16r(ot1[4 * j + 0] * inv);
        st1.y = bf16r(ot1[4 * j + 1] * inv);
        st1.z = bf16r(ot1[4 * j + 2] * inv);
        st1.w = bf16r(ot1[4 * j + 3] * inv);
        *(ushort4*)(op + 8 * j + 4 * hi)      = st0;
        *(ushort4*)(op + 32 + 8 * j + 4 * hi) = st1;
    }
}

// ---------------------------------------------------------------------------
// ws layout (bf16): xb 8MB | Wqt|Wkt|Wvt|Wot 2MB ea | Qb|Kb|Vb|Ab 8MB ea = 48MB
// ---------------------------------------------------------------------------
extern "C" void kernel_launch(void* const* d_in, const int* in_sizes, int n_in,
                              void* d_out, int out_size, void* d_ws, size_t ws_size,
                              hipStream_t stream)
{
    const float* x  = (const float*)d_in[0];
    const float* Wq = (const float*)d_in[1];
    const float* bq = (const float*)d_in[2];
    const float* Wk = (const float*)d_in[3];
    const float* bk = (const float*)d_in[4];
    const float* Wv = (const float*)d_in[5];
    const float* bv = (const float*)d_in[6];
    const float* Wo = (const float*)d_in[7];
    const float* bo = (const float*)d_in[8];

    float* out = (float*)d_out;

    const size_t mat  = (size_t)M_TOTAL * D_MODEL;
    const size_t wmat = (size_t)D_MODEL * D_MODEL;
    unsigned short* xb  = (unsigned short*)d_ws;
    unsigned short* Wqt = xb  + mat;
    unsigned short* Wkt = Wqt + wmat;
    unsigned short* Wvt = Wkt + wmat;
    unsigned short* Wot = Wvt + wmat;
    unsigned short* Qb  = Wot + wmat;
    unsigned short* Kb  = Qb  + mat;
    unsigned short* Vb  = Kb  + mat;
    unsigned short* Ab  = Vb  + mat;

    conv_x<<<dim3(2048), 256, 0, stream>>>(x, xb);
    conv_wt<<<dim3(32, 32, 4), 256, 0, stream>>>(Wq, Wk, Wv, Wo, Wqt, Wkt, Wvt, Wot);

    qkv_mfma<<<dim3(8, 32, 3), 256, 0, stream>>>(xb, Wqt, bq, Wkt, bk, Wvt, bv, Qb, Kb, Vb);

    attn_mfma<<<dim3(SEQ / 128, BATCH * NHEADS), 256, 0, stream>>>(Qb, Kb, Vb, Ab);

    oproj_mfma<<<dim3(8, 32), 256, 0, stream>>>(Ab, Wot, bo, out);
}